// Round 1
// baseline (210.499 us; speedup 1.0000x reference)
//
#include <hip/hip_runtime.h>

__device__ __forceinline__ int refl(int t, int n) {
    if (t < 0) t = -t;
    if (t >= n) t = 2 * (n - 1) - t;
    return t;
}

// down[y][x] = (Gauss5x5 * cur)[2y][2x] with reflect-2 padding
__global__ void down_kernel(const float* __restrict__ cur, float* __restrict__ out,
                            int H, int W, int n) {
    int idx = blockIdx.x * blockDim.x + threadIdx.x;
    if (idx >= n) return;
    int Wh = W >> 1, Hh = H >> 1;
    int x = idx % Wh;
    int t = idx / Wh;
    int y = t % Hh;
    int img = t / Hh;
    const float* base = cur + (size_t)img * H * W;
    const float wv[5] = {1.f, 4.f, 6.f, 4.f, 1.f};
    int cx[5], cy[5];
#pragma unroll
    for (int u = 0; u < 5; ++u) {
        cy[u] = refl(2 * y - 2 + u, H);
        cx[u] = refl(2 * x - 2 + u, W);
    }
    float acc = 0.f;
#pragma unroll
    for (int u = 0; u < 5; ++u) {
        const float* row = base + (size_t)cy[u] * W;
        float rs = 0.f;
#pragma unroll
        for (int v = 0; v < 5; ++v) rs += wv[v] * row[cx[v]];
        acc += wv[u] * rs;
    }
    out[idx] = acc * (1.0f / 256.0f);
}

// lap[i][j] = cur[i][j] - up(down)[i][j]
// up = conv(4*Gauss, reflect-pad(zero-stuff(down)))  ==  parity stencil on down / 64
__global__ void lap_kernel(const float* __restrict__ cur, const float* __restrict__ down,
                           float* __restrict__ out, int H, int W, int n) {
    int idx = blockIdx.x * blockDim.x + threadIdx.x;
    if (idx >= n) return;
    int j = idx % W;
    int t = idx / W;
    int i = t % H;
    int img = t / H;
    int Hh = H >> 1, Wh = W >> 1;

    int ty[3]; float wy[3];
    if ((i & 1) == 0) {
        ty[0] = refl(i - 2, H) >> 1; ty[1] = i >> 1; ty[2] = refl(i + 2, H) >> 1;
        wy[0] = 1.f; wy[1] = 6.f; wy[2] = 1.f;
    } else {
        ty[0] = (i - 1) >> 1; ty[1] = refl(i + 1, H) >> 1; ty[2] = ty[0];
        wy[0] = 4.f; wy[1] = 4.f; wy[2] = 0.f;
    }
    int tx[3]; float wx[3];
    if ((j & 1) == 0) {
        tx[0] = refl(j - 2, W) >> 1; tx[1] = j >> 1; tx[2] = refl(j + 2, W) >> 1;
        wx[0] = 1.f; wx[1] = 6.f; wx[2] = 1.f;
    } else {
        tx[0] = (j - 1) >> 1; tx[1] = refl(j + 1, W) >> 1; tx[2] = tx[0];
        wx[0] = 4.f; wx[1] = 4.f; wx[2] = 0.f;
    }

    const float* dbase = down + (size_t)img * Hh * Wh;
    float up = 0.f;
#pragma unroll
    for (int a = 0; a < 3; ++a) {
        const float* row = dbase + (size_t)ty[a] * Wh;
        float rs = wx[0] * row[tx[0]] + wx[1] * row[tx[1]] + wx[2] * row[tx[2]];
        up += wy[a] * rs;
    }
    out[idx] = cur[idx] - up * (1.0f / 64.0f);
}

extern "C" void kernel_launch(void* const* d_in, const int* in_sizes, int n_in,
                              void* d_out, int out_size, void* d_ws, size_t ws_size,
                              hipStream_t stream) {
    const float* img = (const float*)d_in[0];
    float* out = (float*)d_out;

    const long long BC = 8LL * 3;
    const long long n0 = BC * 1024 * 1024;  // level-0 pixels
    const long long n1 = BC * 512 * 512;
    const long long n2 = BC * 256 * 256;
    const long long n3 = BC * 128 * 128;

    float* out0 = out;                // lap0 (1024^2)
    float* out1 = out0 + n0;          // lap1 (512^2)
    float* out2 = out1 + n1;          // lap2 (256^2)
    float* out3 = out2 + n2;          // down2 (128^2)

    float* ws0 = (float*)d_ws;        // down0: n1 floats
    float* ws1 = ws0 + n1;            // down1: n2 floats

    const int B = 256;
    int n;

    // level 0
    n = (int)n1;
    down_kernel<<<(n + B - 1) / B, B, 0, stream>>>(img, ws0, 1024, 1024, n);
    n = (int)n0;
    lap_kernel<<<(n + B - 1) / B, B, 0, stream>>>(img, ws0, out0, 1024, 1024, n);

    // level 1
    n = (int)n2;
    down_kernel<<<(n + B - 1) / B, B, 0, stream>>>(ws0, ws1, 512, 512, n);
    n = (int)n1;
    lap_kernel<<<(n + B - 1) / B, B, 0, stream>>>(ws0, ws1, out1, 512, 512, n);

    // level 2
    n = (int)n3;
    down_kernel<<<(n + B - 1) / B, B, 0, stream>>>(ws1, out3, 256, 256, n);
    n = (int)n2;
    lap_kernel<<<(n + B - 1) / B, B, 0, stream>>>(ws1, out3, out2, 256, 256, n);
}

// Round 2
// 127.547 us; speedup vs baseline: 1.6504x; 1.6504x over previous
//
#include <hip/hip_runtime.h>

#define TILE 64
#define HALO 4
#define SCW (TILE + 2 * HALO)   // 72: cur tile + halo
#define SDW 34                  // down tile + halo (32 + 2)

__device__ __forceinline__ int refl(int t, int n) {
    if (t < 0) t = -t;
    if (t >= n) t = 2 * (n - 1) - t;
    return t;
}

// One level of the Laplacian pyramid, fused:
//   filtered = gauss5x5_reflect(cur); down = filtered[::2,::2]
//   up = gauss-upsample(down);        lap = cur - up
// Block: 256 threads -> 64x64 output tile of cur (and its 32x32 down tile).
__global__ __launch_bounds__(256) void lap_level_kernel(
    const float* __restrict__ cur, float* __restrict__ lap,
    float* __restrict__ down, int H, int W)
{
    __shared__ float s_cur[SCW][SCW + 1];
    __shared__ float s_down[SDW][SDW + 1];

    const int x0 = blockIdx.x * TILE;
    const int y0 = blockIdx.y * TILE;
    const int img = blockIdx.z;
    const int Hh = H >> 1, Wh = W >> 1;
    const int tid = threadIdx.x;

    const float* curb = cur + (size_t)img * H * W;

    // Phase A: load 72x72 cur tile (reflect at image borders), coalesced rows.
    for (int k = tid; k < SCW * SCW; k += 256) {
        int r = k / SCW, c = k - r * SCW;
        int gy = refl(y0 - HALO + r, H);
        int gx = refl(x0 - HALO + c, W);
        s_cur[r][c] = curb[(size_t)gy * W + gx];
    }
    __syncthreads();

    // Phase B: 34x34 down values. s_down[ty][tx] = down[dy0+ty][dx0+tx],
    // dy0 = y0/2 - 1. down[dy] = sum_{u,v} w[u]w[v] cur[refl(2dy-2+u)][refl(2dx-2+v)]/256
    // -> s_cur window rows 2ty..2ty+4, cols 2tx..2tx+4.
    for (int k = tid; k < SDW * SDW; k += 256) {
        int ty = k / SDW, tx = k - ty * SDW;
        int rb = 2 * ty, cb = 2 * tx;
        const float wv[5] = {1.f, 4.f, 6.f, 4.f, 1.f};
        float acc = 0.f;
#pragma unroll
        for (int u = 0; u < 5; ++u) {
            float rs = 0.f;
#pragma unroll
            for (int v = 0; v < 5; ++v)
                rs += wv[v] * s_cur[rb + u][cb + v];
            acc += wv[u] * rs;
        }
        s_down[ty][tx] = acc * (1.0f / 256.0f);
    }
    __syncthreads();

    const int dy0 = (y0 >> 1) - 1, dx0 = (x0 >> 1) - 1;

    // Phase C1: write interior 32x32 of s_down to global down.
    float* downb = down + (size_t)img * Hh * Wh;
    for (int k = tid; k < 32 * 32; k += 256) {
        int ty = k >> 5, tx = k & 31;
        downb[(size_t)((y0 >> 1) + ty) * Wh + ((x0 >> 1) + tx)] = s_down[ty + 1][tx + 1];
    }

    // Phase C2: lap = cur - up(down). Up at pixel (i,j): parity stencil on down,
    // weights even {1,6,1}, odd {4,4}, scaled 1/64; reflection keeps taps in-image.
    float* lapb = lap + (size_t)img * H * W;
    for (int k = tid; k < TILE * TILE; k += 256) {
        int il = k >> 6, jl = k & 63;
        int i = y0 + il, j = x0 + jl;

        int ty0, ty1, ty2; float wy0, wy1, wy2;
        if ((i & 1) == 0) {
            ty0 = (refl(i - 2, H) >> 1) - dy0; wy0 = 1.f;
            ty1 = (i >> 1) - dy0;              wy1 = 6.f;
            ty2 = (refl(i + 2, H) >> 1) - dy0; wy2 = 1.f;
        } else {
            ty0 = ((i - 1) >> 1) - dy0;        wy0 = 4.f;
            ty1 = (refl(i + 1, H) >> 1) - dy0; wy1 = 4.f;
            ty2 = ty0;                         wy2 = 0.f;
        }
        int tx0, tx1, tx2; float wx0, wx1, wx2;
        if ((j & 1) == 0) {
            tx0 = (refl(j - 2, W) >> 1) - dx0; wx0 = 1.f;
            tx1 = (j >> 1) - dx0;              wx1 = 6.f;
            tx2 = (refl(j + 2, W) >> 1) - dx0; wx2 = 1.f;
        } else {
            tx0 = ((j - 1) >> 1) - dx0;        wx0 = 4.f;
            tx1 = (refl(j + 1, W) >> 1) - dx0; wx1 = 4.f;
            tx2 = tx0;                         wx2 = 0.f;
        }

        float up =
            wy0 * (wx0 * s_down[ty0][tx0] + wx1 * s_down[ty0][tx1] + wx2 * s_down[ty0][tx2]) +
            wy1 * (wx0 * s_down[ty1][tx0] + wx1 * s_down[ty1][tx1] + wx2 * s_down[ty1][tx2]) +
            wy2 * (wx0 * s_down[ty2][tx0] + wx1 * s_down[ty2][tx1] + wx2 * s_down[ty2][tx2]);

        float cv = s_cur[il + HALO][jl + HALO];
        lapb[(size_t)i * W + j] = cv - up * (1.0f / 64.0f);
    }
}

extern "C" void kernel_launch(void* const* d_in, const int* in_sizes, int n_in,
                              void* d_out, int out_size, void* d_ws, size_t ws_size,
                              hipStream_t stream) {
    const float* img = (const float*)d_in[0];
    float* out = (float*)d_out;

    const long long BC = 8LL * 3;
    const long long n0 = BC * 1024 * 1024;
    const long long n1 = BC * 512 * 512;
    const long long n2 = BC * 256 * 256;

    float* out0 = out;            // lap0
    float* out1 = out0 + n0;      // lap1
    float* out2 = out1 + n1;      // lap2
    float* out3 = out2 + n2;      // down2

    float* ws0 = (float*)d_ws;    // down0
    float* ws1 = ws0 + n1;        // down1

    dim3 blk(256);

    lap_level_kernel<<<dim3(1024 / TILE, 1024 / TILE, (int)BC), blk, 0, stream>>>(
        img, out0, ws0, 1024, 1024);
    lap_level_kernel<<<dim3(512 / TILE, 512 / TILE, (int)BC), blk, 0, stream>>>(
        ws0, out1, ws1, 512, 512);
    lap_level_kernel<<<dim3(256 / TILE, 256 / TILE, (int)BC), blk, 0, stream>>>(
        ws1, out2, out3, 256, 256);
}

// Round 3
// 86.768 us; speedup vs baseline: 2.4260x; 1.4700x over previous
//
#include <hip/hip_runtime.h>

#define TILE 64
#define SCW 72          // cur tile + 2*4 halo
#define SCP 76          // s_cur row stride (76*4B = 304B, 16B-aligned rows)
#define SDW 34          // down tile + 2*1 halo
#define SDP 36          // s_down row stride (even -> float2-aligned)

__device__ __forceinline__ int refl(int t, int n) {
    if (t < 0) t = -t;
    if (t >= n) t = 2 * (n - 1) - t;
    return t;
}

// One fused pyramid level: filtered=gauss5(cur); down=filtered[::2,::2];
// lap = cur - up(down). 256 threads -> 64x64 lap tile + 32x32 down tile.
// Thread (tx,ty) in 16x16 grid owns a 4x4 pixel block (= 2x2 down quads).
__global__ __launch_bounds__(256) void lap_level_kernel(
    const float* __restrict__ cur, float* __restrict__ lap,
    float* __restrict__ down, int H, int W)
{
    __shared__ float s_cur[SCW][SCP];
    __shared__ float s_down[SDW][SDP];

    const int x0 = blockIdx.x * TILE, y0 = blockIdx.y * TILE;
    const int img = blockIdx.z;
    const int Hh = H >> 1, Wh = W >> 1;
    const int tid = threadIdx.x;
    const int tx = tid & 15, ty = tid >> 4;

    const float* curb = cur + (size_t)img * H * W;

    // ---- Phase A: stage 72x72 cur tile ----
    const bool border = (x0 == 0) | (y0 == 0) | (x0 + TILE == W) | (y0 + TILE == H);
    if (!border) {
        // branch-free vectorized path: 72 rows x 18 float4
        const float* src = curb + (size_t)(y0 - 4) * W + (x0 - 4);
        for (int k = tid; k < SCW * 18; k += 256) {
            unsigned r = (unsigned)k / 18u;
            unsigned c4 = (unsigned)k - r * 18u;
            *(float4*)&s_cur[r][c4 * 4] =
                *(const float4*)(src + (size_t)r * W + c4 * 4);
        }
    } else {
        for (int k = tid; k < SCW * SCW; k += 256) {
            unsigned r = (unsigned)k / 72u;
            unsigned c = (unsigned)k - r * 72u;
            s_cur[r][c] = curb[(size_t)refl(y0 - 4 + (int)r, H) * W
                               + refl(x0 - 4 + (int)c, W)];
        }
    }
    __syncthreads();

    // ---- Phase B: 34x34 down values (incl. halo ring). Reflection at image
    // borders is inherited from s_cur + kernel symmetry (s_down[0]==down[1],
    // s_down[33]==down[Hh-1]), so phase C never needs border logic. ----
    const int dy0 = (y0 >> 1) - 1, dx0 = (x0 >> 1) - 1;
    float* downb = down + (size_t)img * Hh * Wh;
    for (int k = tid; k < SDW * SDW; k += 256) {
        unsigned dy = (unsigned)k / 34u;
        unsigned dx = (unsigned)k - dy * 34u;
        const int rb = 2 * (int)dy, cb = 2 * (int)dx;
        float acc = 0.f;
        const float wr[5] = {1.f, 4.f, 6.f, 4.f, 1.f};
#pragma unroll
        for (int u = 0; u < 5; ++u) {
            const float* row = &s_cur[rb + u][cb];   // cb even -> 8B aligned
            float2 p0 = *(const float2*)(row);
            float2 p1 = *(const float2*)(row + 2);
            float2 p2 = *(const float2*)(row + 4);
            float rs = p0.x + 4.f * p0.y + 6.f * p1.x + 4.f * p1.y + p2.x;
            acc += wr[u] * rs;
        }
        acc *= (1.0f / 256.0f);
        s_down[dy][dx] = acc;
        if (dy - 1u < 32u && dx - 1u < 32u)          // interior -> global down
            downb[(size_t)(dy0 + (int)dy) * Wh + (dx0 + (int)dx)] = acc;
    }
    __syncthreads();

    // ---- Phase C: lap = cur - up(down), 4x4 pixels per thread ----
    // d[r][c] = s_down[2ty+r][2tx+c]; quad (r2,c2) covers pixels
    // (y0+4ty+2r2+{0,1}, x0+4tx+2c2+{0,1}); parity weights are compile-time.
    float d[4][4];
#pragma unroll
    for (int r = 0; r < 4; ++r) {
        float2 a = *(const float2*)&s_down[2 * ty + r][2 * tx];
        float2 b = *(const float2*)&s_down[2 * ty + r][2 * tx + 2];
        d[r][0] = a.x; d[r][1] = a.y; d[r][2] = b.x; d[r][3] = b.y;
    }
    float ve[2][4], vo[2][4];   // column sums: even rows {1,6,1}, odd {4,4}
#pragma unroll
    for (int r2 = 0; r2 < 2; ++r2)
#pragma unroll
        for (int c = 0; c < 4; ++c) {
            ve[r2][c] = d[r2][c] + 6.f * d[r2 + 1][c] + d[r2 + 2][c];
            vo[r2][c] = 4.f * (d[r2 + 1][c] + d[r2 + 2][c]);
        }

    float* lapb = lap + (size_t)img * H * W;
    const int ib = y0 + 4 * ty, jb = x0 + 4 * tx;
#pragma unroll
    for (int rr = 0; rr < 4; ++rr) {
        const int r2 = rr >> 1;
        float4 cv = *(const float4*)&s_cur[4 * ty + 4 + rr][4 * tx + 4];
        float u0, u1, u2, u3;
        if ((rr & 1) == 0) {
            u0 = ve[r2][0] + 6.f * ve[r2][1] + ve[r2][2];
            u1 = 4.f * (ve[r2][1] + ve[r2][2]);
            u2 = ve[r2][1] + 6.f * ve[r2][2] + ve[r2][3];
            u3 = 4.f * (ve[r2][2] + ve[r2][3]);
        } else {
            u0 = vo[r2][0] + 6.f * vo[r2][1] + vo[r2][2];
            u1 = 4.f * (vo[r2][1] + vo[r2][2]);
            u2 = vo[r2][1] + 6.f * vo[r2][2] + vo[r2][3];
            u3 = 4.f * (vo[r2][2] + vo[r2][3]);
        }
        float4 o;
        o.x = cv.x - u0 * (1.f / 64.f);
        o.y = cv.y - u1 * (1.f / 64.f);
        o.z = cv.z - u2 * (1.f / 64.f);
        o.w = cv.w - u3 * (1.f / 64.f);
        *(float4*)(lapb + (size_t)(ib + rr) * W + jb) = o;
    }
}

extern "C" void kernel_launch(void* const* d_in, const int* in_sizes, int n_in,
                              void* d_out, int out_size, void* d_ws, size_t ws_size,
                              hipStream_t stream) {
    const float* img = (const float*)d_in[0];
    float* out = (float*)d_out;

    const long long BC = 8LL * 3;
    const long long n0 = BC * 1024 * 1024;
    const long long n1 = BC * 512 * 512;
    const long long n2 = BC * 256 * 256;

    float* out0 = out;            // lap0
    float* out1 = out0 + n0;      // lap1
    float* out2 = out1 + n1;      // lap2
    float* out3 = out2 + n2;      // down2

    float* ws0 = (float*)d_ws;    // down0
    float* ws1 = ws0 + n1;        // down1

    lap_level_kernel<<<dim3(1024 / TILE, 1024 / TILE, (int)BC), 256, 0, stream>>>(
        img, out0, ws0, 1024, 1024);
    lap_level_kernel<<<dim3(512 / TILE, 512 / TILE, (int)BC), 256, 0, stream>>>(
        ws0, out1, ws1, 512, 512);
    lap_level_kernel<<<dim3(256 / TILE, 256 / TILE, (int)BC), 256, 0, stream>>>(
        ws1, out2, out3, 256, 256);
}

// Round 4
// 86.482 us; speedup vs baseline: 2.4340x; 1.0033x over previous
//
#include <hip/hip_runtime.h>

#define TILE 64

__device__ __forceinline__ int refl(int t, int n) {
    if (t < 0) t = -t;
    if (t >= n) t = 2 * (n - 1) - t;
    return t;
}

// ================= fused levels 0+1 =================
// Per 64x64 tile of cur: stage 83x83 cur (halo 12 top/left for 16B alignment,
// covers rows y0-12..y0+70), chain down0 (39x39, rows y0/2-4..+34) and
// down1 (18x18, rows y0/4-1..+16) in LDS. Outputs: lap0 64x64, lap1 32x32,
// down1 16x16 (-> global, feeds level-2 kernel). down0 never touches HBM.
#define SC_H 83
#define SC_W 84   // row stride, 84*4B = 336B (16B multiple)
#define D0_N 39
#define D0_P 40
#define D1_N 18
#define D1_P 20

__global__ __launch_bounds__(256) void lap2level_kernel(
    const float* __restrict__ cur, float* __restrict__ lap0,
    float* __restrict__ lap1, float* __restrict__ down1,
    int H, int W)
{
    __shared__ float s_cur[SC_H][SC_W];
    __shared__ float s_d0[D0_N][D0_P];
    __shared__ float s_d1[D1_N][D1_P];

    const int x0 = blockIdx.x * TILE, y0 = blockIdx.y * TILE;
    const int img = blockIdx.z;
    const int Hh = H >> 1, Wh = W >> 1, Wq = W >> 2;
    const int tid = threadIdx.x;
    const int tx = tid & 15, ty = tid >> 4;

    const float* curb = cur + (size_t)img * H * W;

    // ---- A: stage cur tile ----
    const bool border = (x0 == 0) | (y0 == 0) | (x0 + TILE == W) | (y0 + TILE == H);
    if (!border) {
        const float* src = curb + (size_t)(y0 - 12) * W + (x0 - 12);
        for (int k = tid; k < SC_H * 21; k += 256) {
            unsigned r = (unsigned)k / 21u;
            unsigned c4 = (unsigned)k - r * 21u;
            *(float4*)&s_cur[r][c4 * 4] = *(const float4*)(src + (size_t)r * W + c4 * 4);
        }
    } else {
        for (int k = tid; k < SC_H * SC_H; k += 256) {
            unsigned r = (unsigned)k / 83u;
            unsigned c = (unsigned)k - r * 83u;
            s_cur[r][c] = curb[(size_t)refl(y0 - 12 + (int)r, H) * W
                               + refl(x0 - 12 + (int)c, W)];
        }
    }
    __syncthreads();

    // ---- B: down0 39x39 (chain convention at halo: virtual d0[-k]=d0[k],
    //         d0[Hh-1+k]=d0[Hh-k] -- exactly what lap0's up-stencil needs) ----
    for (int k = tid; k < D0_N * D0_N; k += 256) {
        unsigned a = (unsigned)k / 39u;
        unsigned b = (unsigned)k - a * 39u;
        const int rb = 2 * (int)a + 2, cb = 2 * (int)b + 2;  // cb even -> 8B aligned
        const float wv[5] = {1.f, 4.f, 6.f, 4.f, 1.f};
        float acc = 0.f;
#pragma unroll
        for (int u = 0; u < 5; ++u) {
            const float* row = &s_cur[rb + u][cb];
            float2 p0 = *(const float2*)row;
            float2 p1 = *(const float2*)(row + 2);
            float rs = p0.x + 4.f * p0.y + 6.f * p1.x + 4.f * p1.y + row[4];
            acc += wv[u] * rs;
        }
        s_d0[a][b] = acc * (1.0f / 256.0f);
    }
    __syncthreads();

    // ---- D: down1 18x18. Next-level conv needs TRUE reflect on down0, which
    // differs from chain convention only past the bottom/right image edge:
    // remap tap a -> a - 2*max(dy-(Hh-1),0) into the true-reflect slot. ----
    const int dy0f = (y0 >> 1) - 4, dx0f = (x0 >> 1) - 4;
    for (int k = tid; k < D1_N * D1_N; k += 256) {
        unsigned e = (unsigned)k / 18u;
        unsigned f = (unsigned)k - e * 18u;
        int ar[5], bc[5];
#pragma unroll
        for (int u = 0; u < 5; ++u) {
            int dyt = dy0f + 2 * (int)e + u;
            int ov = dyt - (Hh - 1); if (ov < 0) ov = 0;
            ar[u] = 2 * (int)e + u - 2 * ov;
            int dxt = dx0f + 2 * (int)f + u;
            int ow = dxt - (Wh - 1); if (ow < 0) ow = 0;
            bc[u] = 2 * (int)f + u - 2 * ow;
        }
        const float wv[5] = {1.f, 4.f, 6.f, 4.f, 1.f};
        float acc = 0.f;
#pragma unroll
        for (int u = 0; u < 5; ++u) {
            float rs = 0.f;
#pragma unroll
            for (int v = 0; v < 5; ++v) rs += wv[v] * s_d0[ar[u]][bc[v]];
            acc += wv[u] * rs;
        }
        s_d1[e][f] = acc * (1.0f / 256.0f);
    }
    __syncthreads();

    // ---- E: write down1 interior 16x16 (1 value/thread) ----
    {
        float* d1b = down1 + (size_t)img * (Hh >> 1) * Wq;
        int e = (tid >> 4) + 1, f = (tid & 15) + 1;
        d1b[(size_t)((y0 >> 2) + e - 1) * Wq + ((x0 >> 2) + f - 1)] = s_d1[e][f];
    }

    // ---- F: lap0 = cur - up(down0), 4x4 px/thread, compile-time parity ----
    {
        float d[4][4];
#pragma unroll
        for (int r = 0; r < 4; ++r)
#pragma unroll
            for (int c = 0; c < 4; ++c)
                d[r][c] = s_d0[2 * ty + 3 + r][2 * tx + 3 + c];
        float ve[2][4], vo[2][4];
#pragma unroll
        for (int r2 = 0; r2 < 2; ++r2)
#pragma unroll
            for (int c = 0; c < 4; ++c) {
                ve[r2][c] = d[r2][c] + 6.f * d[r2 + 1][c] + d[r2 + 2][c];
                vo[r2][c] = 4.f * (d[r2 + 1][c] + d[r2 + 2][c]);
            }
        float* lap0b = lap0 + (size_t)img * H * W;
        const int ib = y0 + 4 * ty, jb = x0 + 4 * tx;
#pragma unroll
        for (int rr = 0; rr < 4; ++rr) {
            const int r2 = rr >> 1;
            float4 cv = *(const float4*)&s_cur[4 * ty + 12 + rr][4 * tx + 12];
            float u0, u1, u2, u3;
            if ((rr & 1) == 0) {
                u0 = ve[r2][0] + 6.f * ve[r2][1] + ve[r2][2];
                u1 = 4.f * (ve[r2][1] + ve[r2][2]);
                u2 = ve[r2][1] + 6.f * ve[r2][2] + ve[r2][3];
                u3 = 4.f * (ve[r2][2] + ve[r2][3]);
            } else {
                u0 = vo[r2][0] + 6.f * vo[r2][1] + vo[r2][2];
                u1 = 4.f * (vo[r2][1] + vo[r2][2]);
                u2 = vo[r2][1] + 6.f * vo[r2][2] + vo[r2][3];
                u3 = 4.f * (vo[r2][2] + vo[r2][3]);
            }
            float4 o;
            o.x = cv.x - u0 * (1.f / 64.f);
            o.y = cv.y - u1 * (1.f / 64.f);
            o.z = cv.z - u2 * (1.f / 64.f);
            o.w = cv.w - u3 * (1.f / 64.f);
            *(float4*)(lap0b + (size_t)(ib + rr) * W + jb) = o;
        }
    }

    // ---- G: lap1 = down0 - up(down1), 2x2 px/thread ----
    {
        float m[3][3];
#pragma unroll
        for (int a = 0; a < 3; ++a)
#pragma unroll
            for (int b = 0; b < 3; ++b)
                m[a][b] = s_d1[ty + a][tx + b];
        float ce[3], co[3];
#pragma unroll
        for (int c = 0; c < 3; ++c) {
            ce[c] = m[0][c] + 6.f * m[1][c] + m[2][c];
            co[c] = 4.f * (m[1][c] + m[2][c]);
        }
        float u00 = ce[0] + 6.f * ce[1] + ce[2];
        float u01 = 4.f * (ce[1] + ce[2]);
        float u10 = co[0] + 6.f * co[1] + co[2];
        float u11 = 4.f * (co[1] + co[2]);
        float2 c0 = *(const float2*)&s_d0[2 * ty + 4][2 * tx + 4];
        float2 c1 = *(const float2*)&s_d0[2 * ty + 5][2 * tx + 4];
        float* lap1b = lap1 + (size_t)img * Hh * Wh;
        const int p0 = (y0 >> 1) + 2 * ty, q0 = (x0 >> 1) + 2 * tx;
        float2 o0, o1;
        o0.x = c0.x - u00 * (1.f / 64.f);
        o0.y = c0.y - u01 * (1.f / 64.f);
        o1.x = c1.x - u10 * (1.f / 64.f);
        o1.y = c1.y - u11 * (1.f / 64.f);
        *(float2*)(lap1b + (size_t)p0 * Wh + q0) = o0;
        *(float2*)(lap1b + (size_t)(p0 + 1) * Wh + q0) = o1;
    }
}

// ================= single level (used for level 2) =================
#define SCW 72
#define SCP 76
#define SDW 34
#define SDP 36

__global__ __launch_bounds__(256) void lap_level_kernel(
    const float* __restrict__ cur, float* __restrict__ lap,
    float* __restrict__ down, int H, int W)
{
    __shared__ float s_cur[SCW][SCP];
    __shared__ float s_down[SDW][SDP];

    const int x0 = blockIdx.x * TILE, y0 = blockIdx.y * TILE;
    const int img = blockIdx.z;
    const int Hh = H >> 1, Wh = W >> 1;
    const int tid = threadIdx.x;
    const int tx = tid & 15, ty = tid >> 4;

    const float* curb = cur + (size_t)img * H * W;

    const bool border = (x0 == 0) | (y0 == 0) | (x0 + TILE == W) | (y0 + TILE == H);
    if (!border) {
        const float* src = curb + (size_t)(y0 - 4) * W + (x0 - 4);
        for (int k = tid; k < SCW * 18; k += 256) {
            unsigned r = (unsigned)k / 18u;
            unsigned c4 = (unsigned)k - r * 18u;
            *(float4*)&s_cur[r][c4 * 4] = *(const float4*)(src + (size_t)r * W + c4 * 4);
        }
    } else {
        for (int k = tid; k < SCW * SCW; k += 256) {
            unsigned r = (unsigned)k / 72u;
            unsigned c = (unsigned)k - r * 72u;
            s_cur[r][c] = curb[(size_t)refl(y0 - 4 + (int)r, H) * W
                               + refl(x0 - 4 + (int)c, W)];
        }
    }
    __syncthreads();

    const int dy0 = (y0 >> 1) - 1, dx0 = (x0 >> 1) - 1;
    float* downb = down + (size_t)img * Hh * Wh;
    for (int k = tid; k < SDW * SDW; k += 256) {
        unsigned dy = (unsigned)k / 34u;
        unsigned dx = (unsigned)k - dy * 34u;
        const int rb = 2 * (int)dy, cb = 2 * (int)dx;
        const float wv[5] = {1.f, 4.f, 6.f, 4.f, 1.f};
        float acc = 0.f;
#pragma unroll
        for (int u = 0; u < 5; ++u) {
            const float* row = &s_cur[rb + u][cb];
            float2 p0 = *(const float2*)(row);
            float2 p1 = *(const float2*)(row + 2);
            float rs = p0.x + 4.f * p0.y + 6.f * p1.x + 4.f * p1.y + row[4];
            acc += wv[u] * rs;
        }
        acc *= (1.0f / 256.0f);
        s_down[dy][dx] = acc;
        if (dy - 1u < 32u && dx - 1u < 32u)
            downb[(size_t)(dy0 + (int)dy) * Wh + (dx0 + (int)dx)] = acc;
    }
    __syncthreads();

    float d[4][4];
#pragma unroll
    for (int r = 0; r < 4; ++r) {
        float2 a = *(const float2*)&s_down[2 * ty + r][2 * tx];
        float2 b = *(const float2*)&s_down[2 * ty + r][2 * tx + 2];
        d[r][0] = a.x; d[r][1] = a.y; d[r][2] = b.x; d[r][3] = b.y;
    }
    float ve[2][4], vo[2][4];
#pragma unroll
    for (int r2 = 0; r2 < 2; ++r2)
#pragma unroll
        for (int c = 0; c < 4; ++c) {
            ve[r2][c] = d[r2][c] + 6.f * d[r2 + 1][c] + d[r2 + 2][c];
            vo[r2][c] = 4.f * (d[r2 + 1][c] + d[r2 + 2][c]);
        }

    float* lapb = lap + (size_t)img * H * W;
    const int ib = y0 + 4 * ty, jb = x0 + 4 * tx;
#pragma unroll
    for (int rr = 0; rr < 4; ++rr) {
        const int r2 = rr >> 1;
        float4 cv = *(const float4*)&s_cur[4 * ty + 4 + rr][4 * tx + 4];
        float u0, u1, u2, u3;
        if ((rr & 1) == 0) {
            u0 = ve[r2][0] + 6.f * ve[r2][1] + ve[r2][2];
            u1 = 4.f * (ve[r2][1] + ve[r2][2]);
            u2 = ve[r2][1] + 6.f * ve[r2][2] + ve[r2][3];
            u3 = 4.f * (ve[r2][2] + ve[r2][3]);
        } else {
            u0 = vo[r2][0] + 6.f * vo[r2][1] + vo[r2][2];
            u1 = 4.f * (vo[r2][1] + vo[r2][2]);
            u2 = vo[r2][1] + 6.f * vo[r2][2] + vo[r2][3];
            u3 = 4.f * (vo[r2][2] + vo[r2][3]);
        }
        float4 o;
        o.x = cv.x - u0 * (1.f / 64.f);
        o.y = cv.y - u1 * (1.f / 64.f);
        o.z = cv.z - u2 * (1.f / 64.f);
        o.w = cv.w - u3 * (1.f / 64.f);
        *(float4*)(lapb + (size_t)(ib + rr) * W + jb) = o;
    }
}

extern "C" void kernel_launch(void* const* d_in, const int* in_sizes, int n_in,
                              void* d_out, int out_size, void* d_ws, size_t ws_size,
                              hipStream_t stream) {
    const float* img = (const float*)d_in[0];
    float* out = (float*)d_out;

    const long long BC = 8LL * 3;
    const long long n0 = BC * 1024 * 1024;
    const long long n1 = BC * 512 * 512;
    const long long n2 = BC * 256 * 256;

    float* out0 = out;            // lap0
    float* out1 = out0 + n0;      // lap1
    float* out2 = out1 + n1;      // lap2
    float* out3 = out2 + n2;      // down2

    float* ws0 = (float*)d_ws;    // down1 (24 x 256 x 256)

    lap2level_kernel<<<dim3(16, 16, (int)BC), 256, 0, stream>>>(
        img, out0, out1, ws0, 1024, 1024);
    lap_level_kernel<<<dim3(256 / TILE, 256 / TILE, (int)BC), 256, 0, stream>>>(
        ws0, out2, out3, 256, 256);
}

// Round 5
// 84.485 us; speedup vs baseline: 2.4916x; 1.0236x over previous
//
#include <hip/hip_runtime.h>

#define TILE 64
#define SCP 76   // s_cur row stride (304B, 16B-aligned)
#define TMP 77   // s_tmp row stride (odd -> bank-spread for stride-2 reads)
#define SDP 35   // s_down row stride (odd)

__device__ __forceinline__ int refl(int t, int n) {
    if (t < 0) t = -t;
    if (t >= n) t = 2 * (n - 1) - t;
    return t;
}

// One fused pyramid level: down = gauss5(cur)[::2,::2]; lap = cur - up(down).
// 512 threads per 64x64 tile; separable 5x5; 37.1KB LDS -> 4 blocks/CU = 32 waves.
__global__ __launch_bounds__(512, 8) void lap_level_kernel(
    const float* __restrict__ cur, float* __restrict__ lap,
    float* __restrict__ down, int H, int W)
{
    __shared__ float s_cur[72][SCP];
    __shared__ float s_tmp[34][TMP];   // vertical-filtered, even rows
    __shared__ float s_down[34][SDP];  // down tile + 1-ring halo

    const int x0 = blockIdx.x * TILE, y0 = blockIdx.y * TILE;
    const int img = blockIdx.z;
    const int Hh = H >> 1, Wh = W >> 1;
    const int tid = threadIdx.x;

    const float* curb = cur + (size_t)img * H * W;

    // ---- A: stage 72x72 cur tile (rows y0-4..y0+67) ----
    const bool border = (x0 == 0) | (y0 == 0) | (x0 + TILE == W) | (y0 + TILE == H);
    if (!border) {
        const float* src = curb + (size_t)(y0 - 4) * W + (x0 - 4);
        for (int k = tid; k < 72 * 18; k += 512) {
            unsigned r = (unsigned)k / 18u;
            unsigned c4 = ((unsigned)k - r * 18u) * 4u;
            *(float4*)&s_cur[r][c4] = *(const float4*)(src + (size_t)r * W + c4);
        }
    } else {
        for (int k = tid; k < 72 * 72; k += 512) {
            unsigned r = (unsigned)k / 72u;
            unsigned c = (unsigned)k - r * 72u;
            s_cur[r][c] = curb[(size_t)refl(y0 - 4 + (int)r, H) * W
                               + refl(x0 - 4 + (int)c, W)];
        }
    }
    __syncthreads();

    // ---- Bv: vertical 5-tap at even rows: tmp[a][c] = sum_u w[u] cur[2a+u][c] ----
    for (int k = tid; k < 34 * 18; k += 512) {
        unsigned a = (unsigned)k / 18u;
        unsigned c4 = ((unsigned)k - a * 18u) * 4u;
        float4 r0 = *(const float4*)&s_cur[2 * a + 0][c4];
        float4 r1 = *(const float4*)&s_cur[2 * a + 1][c4];
        float4 r2 = *(const float4*)&s_cur[2 * a + 2][c4];
        float4 r3 = *(const float4*)&s_cur[2 * a + 3][c4];
        float4 r4 = *(const float4*)&s_cur[2 * a + 4][c4];
        s_tmp[a][c4 + 0] = r0.x + 4.f * r1.x + 6.f * r2.x + 4.f * r3.x + r4.x;
        s_tmp[a][c4 + 1] = r0.y + 4.f * r1.y + 6.f * r2.y + 4.f * r3.y + r4.y;
        s_tmp[a][c4 + 2] = r0.z + 4.f * r1.z + 6.f * r2.z + 4.f * r3.z + r4.z;
        s_tmp[a][c4 + 3] = r0.w + 4.f * r1.w + 6.f * r2.w + 4.f * r3.w + r4.w;
    }
    __syncthreads();

    // ---- Bh: horizontal 5-tap -> s_down (34x34 incl. halo ring); interior to HBM.
    // Halo follows chain convention (inherited reflect + kernel symmetry), which
    // is exactly what the up-stencil needs. ----
    float* downb = down + (size_t)img * Hh * Wh;
    for (int k = tid; k < 34 * 34; k += 512) {
        unsigned a = (unsigned)k / 34u;
        unsigned b = (unsigned)k - a * 34u;
        const float* t = &s_tmp[a][2 * b];
        float v = (t[0] + 4.f * t[1] + 6.f * t[2] + 4.f * t[3] + t[4]) * (1.f / 256.f);
        s_down[a][b] = v;
        if (a - 1u < 32u && b - 1u < 32u)
            downb[(size_t)((y0 >> 1) + (int)a - 1) * Wh + ((x0 >> 1) + (int)b - 1)] = v;
    }
    __syncthreads();

    // ---- C: lap = cur - up(down); 4 wide x 2 tall px/thread, parity compile-time.
    // Even row i=2ty: d rows ty..ty+2 w {1,6,1}; odd row: rows ty+1,ty+2 w {4,4}. ----
    const int tx = tid & 15, ty = tid >> 4;   // tx 0..15, ty 0..31
    float d0[4], d1[4], d2[4];
#pragma unroll
    for (int c = 0; c < 4; ++c) {
        d0[c] = s_down[ty + 0][2 * tx + c];
        d1[c] = s_down[ty + 1][2 * tx + c];
        d2[c] = s_down[ty + 2][2 * tx + c];
    }
    float ce[4], co[4];
#pragma unroll
    for (int c = 0; c < 4; ++c) {
        ce[c] = d0[c] + 6.f * d1[c] + d2[c];
        co[c] = 4.f * (d1[c] + d2[c]);
    }
    float4 cve = *(const float4*)&s_cur[4 + 2 * ty][4 + 4 * tx];
    float4 cvo = *(const float4*)&s_cur[5 + 2 * ty][4 + 4 * tx];
    float4 oe, oo;
    oe.x = cve.x - (ce[0] + 6.f * ce[1] + ce[2]) * (1.f / 64.f);
    oe.y = cve.y - 4.f * (ce[1] + ce[2]) * (1.f / 64.f);
    oe.z = cve.z - (ce[1] + 6.f * ce[2] + ce[3]) * (1.f / 64.f);
    oe.w = cve.w - 4.f * (ce[2] + ce[3]) * (1.f / 64.f);
    oo.x = cvo.x - (co[0] + 6.f * co[1] + co[2]) * (1.f / 64.f);
    oo.y = cvo.y - 4.f * (co[1] + co[2]) * (1.f / 64.f);
    oo.z = cvo.z - (co[1] + 6.f * co[2] + co[3]) * (1.f / 64.f);
    oo.w = cvo.w - 4.f * (co[2] + co[3]) * (1.f / 64.f);

    float* lapb = lap + (size_t)img * H * W;
    const int i0 = y0 + 2 * ty, j0 = x0 + 4 * tx;
    *(float4*)(lapb + (size_t)i0 * W + j0) = oe;
    *(float4*)(lapb + (size_t)(i0 + 1) * W + j0) = oo;
}

extern "C" void kernel_launch(void* const* d_in, const int* in_sizes, int n_in,
                              void* d_out, int out_size, void* d_ws, size_t ws_size,
                              hipStream_t stream) {
    const float* img = (const float*)d_in[0];
    float* out = (float*)d_out;

    const long long BC = 8LL * 3;
    const long long n0 = BC * 1024 * 1024;
    const long long n1 = BC * 512 * 512;
    const long long n2 = BC * 256 * 256;

    float* out0 = out;            // lap0
    float* out1 = out0 + n0;      // lap1
    float* out2 = out1 + n1;      // lap2
    float* out3 = out2 + n2;      // down2

    float* ws0 = (float*)d_ws;    // down0
    float* ws1 = ws0 + n1;        // down1

    lap_level_kernel<<<dim3(1024 / TILE, 1024 / TILE, (int)BC), 512, 0, stream>>>(
        img, out0, ws0, 1024, 1024);
    lap_level_kernel<<<dim3(512 / TILE, 512 / TILE, (int)BC), 512, 0, stream>>>(
        ws0, out1, ws1, 512, 512);
    lap_level_kernel<<<dim3(256 / TILE, 256 / TILE, (int)BC), 512, 0, stream>>>(
        ws1, out2, out3, 256, 256);
}

// Round 6
// 81.033 us; speedup vs baseline: 2.5977x; 1.0426x over previous
//
#include <hip/hip_runtime.h>

#define TW 64        // tile width  (lap pixels)
#define TH 32        // tile height
#define DR 18        // down rows incl. 1-ring halo (TH/2 + 2)
#define DC 34        // down cols incl. halo (TW/2 + 2)
#define TMPP 76      // s_tmp row stride (16B-aligned rows: 76*4B)
#define SDP 35       // s_down row stride (odd -> bank spread)

__device__ __forceinline__ int refl(int t, int n) {
    if (t < 0) t = -t;
    if (t >= n) t = 2 * (n - 1) - t;
    return t;
}

// One fused pyramid level: down = gauss5(cur)[::2,::2]; lap = cur - up(down).
// No cur staging: vertical pass reads global directly (L1/L2 serve the 2.5x
// row redundancy); lap's cur values re-read from global (always in-image).
// 256 threads, 64x32 tile, 8.0KB LDS -> 8 blocks/CU = 32 waves, 8 barrier
// domains. Halo down values follow the chain convention (reflect inherited
// from the reflected reads + kernel symmetry) which is exactly what the
// up-stencil needs; absmax validated in R3/R5.
__global__ __launch_bounds__(256, 8) void lap_level_kernel(
    const float* __restrict__ cur, float* __restrict__ lap,
    float* __restrict__ down, int H, int W)
{
    __shared__ float s_tmp[DR][TMPP];   // vertical 5-tap at even rows, cols x0-4..x0+67
    __shared__ float s_down[DR][SDP];   // down tile + halo ring

    const int x0 = blockIdx.x * TW, y0 = blockIdx.y * TH;
    const int img = blockIdx.z;
    const int Hh = H >> 1, Wh = W >> 1;
    const int tid = threadIdx.x;

    const float* curb = cur + (size_t)img * H * W;

    // ---- Bv: tmp[a][c] = sum_u w[u] * cur[y0+2a-4+u][x0-4+c], c in 0..71 ----
    const bool border = (x0 == 0) | (y0 == 0) | (x0 + TW == W) | (y0 + TH == H);
    if (!border) {
        for (int k = tid; k < DR * 18; k += 256) {
            unsigned a = (unsigned)k / 18u;
            unsigned c4 = ((unsigned)k - a * 18u) * 4u;
            const float* p = curb + (size_t)(y0 + 2 * (int)a - 4) * W + (x0 - 4 + (int)c4);
            float4 r0 = *(const float4*)(p);
            float4 r1 = *(const float4*)(p + (size_t)W);
            float4 r2 = *(const float4*)(p + (size_t)2 * W);
            float4 r3 = *(const float4*)(p + (size_t)3 * W);
            float4 r4 = *(const float4*)(p + (size_t)4 * W);
            float4 t;
            t.x = r0.x + 4.f * r1.x + 6.f * r2.x + 4.f * r3.x + r4.x;
            t.y = r0.y + 4.f * r1.y + 6.f * r2.y + 4.f * r3.y + r4.y;
            t.z = r0.z + 4.f * r1.z + 6.f * r2.z + 4.f * r3.z + r4.z;
            t.w = r0.w + 4.f * r1.w + 6.f * r2.w + 4.f * r3.w + r4.w;
            *(float4*)&s_tmp[a][c4] = t;
        }
    } else {
        for (int k = tid; k < DR * 72; k += 256) {
            unsigned a = (unsigned)k / 72u;
            unsigned c = (unsigned)k - a * 72u;
            int gx = refl(x0 - 4 + (int)c, W);
            int r0 = y0 + 2 * (int)a - 4;
            float acc = 0.f;
            const float wv[5] = {1.f, 4.f, 6.f, 4.f, 1.f};
#pragma unroll
            for (int u = 0; u < 5; ++u)
                acc += wv[u] * curb[(size_t)refl(r0 + u, H) * W + gx];
            s_tmp[a][c] = acc;
        }
    }
    __syncthreads();

    // ---- Bh: two down outputs per iter from two aligned float4 reads ----
    float* downb = down + (size_t)img * Hh * Wh;
    for (int k = tid; k < DR * 17; k += 256) {
        unsigned a = (unsigned)k / 17u;
        unsigned b2 = (unsigned)k - a * 17u;
        float4 A = *(const float4*)&s_tmp[a][4 * b2];
        float4 B = *(const float4*)&s_tmp[a][4 * b2 + 4];
        float v0 = (A.x + 4.f * A.y + 6.f * A.z + 4.f * A.w + B.x) * (1.f / 256.f);
        float v1 = (A.z + 4.f * A.w + 6.f * B.x + 4.f * B.y + B.z) * (1.f / 256.f);
        s_down[a][2 * b2] = v0;
        s_down[a][2 * b2 + 1] = v1;
        if (a - 1u < 16u) {                       // interior down rows
            size_t rowoff = (size_t)((y0 >> 1) - 1 + (int)a) * Wh + ((x0 >> 1) - 1);
            if (b2 >= 1u) downb[rowoff + 2 * b2] = v0;        // col in [1,32]
            if (b2 <= 15u) downb[rowoff + 2 * b2 + 1] = v1;
        }
    }
    __syncthreads();

    // ---- C: lap = cur - up(down); thread = 4 wide x 2 tall; parity static ----
    const int tx = tid & 15, ty = tid >> 4;
    float d0[4], d1[4], d2[4];
#pragma unroll
    for (int c = 0; c < 4; ++c) {
        d0[c] = s_down[ty + 0][2 * tx + c];
        d1[c] = s_down[ty + 1][2 * tx + c];
        d2[c] = s_down[ty + 2][2 * tx + c];
    }
    float ce[4], co[4];
#pragma unroll
    for (int c = 0; c < 4; ++c) {
        ce[c] = d0[c] + 6.f * d1[c] + d2[c];
        co[c] = 4.f * (d1[c] + d2[c]);
    }
    const int i0 = y0 + 2 * ty, j0 = x0 + 4 * tx;
    const float* cvp = curb + (size_t)i0 * W + j0;
    float4 cve = *(const float4*)(cvp);
    float4 cvo = *(const float4*)(cvp + (size_t)W);
    float4 oe, oo;
    oe.x = cve.x - (ce[0] + 6.f * ce[1] + ce[2]) * (1.f / 64.f);
    oe.y = cve.y - 4.f * (ce[1] + ce[2]) * (1.f / 64.f);
    oe.z = cve.z - (ce[1] + 6.f * ce[2] + ce[3]) * (1.f / 64.f);
    oe.w = cve.w - 4.f * (ce[2] + ce[3]) * (1.f / 64.f);
    oo.x = cvo.x - (co[0] + 6.f * co[1] + co[2]) * (1.f / 64.f);
    oo.y = cvo.y - 4.f * (co[1] + co[2]) * (1.f / 64.f);
    oo.z = cvo.z - (co[1] + 6.f * co[2] + co[3]) * (1.f / 64.f);
    oo.w = cvo.w - 4.f * (co[2] + co[3]) * (1.f / 64.f);

    float* lapb = lap + (size_t)img * H * W;
    *(float4*)(lapb + (size_t)i0 * W + j0) = oe;
    *(float4*)(lapb + (size_t)(i0 + 1) * W + j0) = oo;
}

extern "C" void kernel_launch(void* const* d_in, const int* in_sizes, int n_in,
                              void* d_out, int out_size, void* d_ws, size_t ws_size,
                              hipStream_t stream) {
    const float* img = (const float*)d_in[0];
    float* out = (float*)d_out;

    const long long BC = 8LL * 3;
    const long long n0 = BC * 1024 * 1024;
    const long long n1 = BC * 512 * 512;
    const long long n2 = BC * 256 * 256;

    float* out0 = out;            // lap0
    float* out1 = out0 + n0;      // lap1
    float* out2 = out1 + n1;      // lap2
    float* out3 = out2 + n2;      // down2

    float* ws0 = (float*)d_ws;    // down0
    float* ws1 = ws0 + n1;        // down1

    lap_level_kernel<<<dim3(1024 / TW, 1024 / TH, (int)BC), 256, 0, stream>>>(
        img, out0, ws0, 1024, 1024);
    lap_level_kernel<<<dim3(512 / TW, 512 / TH, (int)BC), 256, 0, stream>>>(
        ws0, out1, ws1, 512, 512);
    lap_level_kernel<<<dim3(256 / TW, 256 / TH, (int)BC), 256, 0, stream>>>(
        ws1, out2, out3, 256, 256);
}